// Round 1
// baseline (110.344 us; speedup 1.0000x reference)
//
#include <hip/hip_runtime.h>

// ConvAutoEncoder: B=16384, T=64, C=2, D=4
// out = [encoder_out (B*64*2 f32) | decoded (B*128 f32)]

typedef __attribute__((ext_vector_type(8))) short bf16x8;
typedef __attribute__((ext_vector_type(4))) float f32x4;

__device__ __forceinline__ unsigned short f2bf(float f) {
    unsigned int u = __builtin_bit_cast(unsigned int, f);
    return (unsigned short)((u + 0x7FFFu + ((u >> 16) & 1u)) >> 16);
}

// ---------------- kernel 0: weight prep (f32 -> bf16 in ws) ----------------
__global__ void k0_prep(const float* __restrict__ w1, const float* __restrict__ w2,
                        unsigned short* __restrict__ w1b, unsigned short* __restrict__ w2b) {
    int i = blockIdx.x * 256 + threadIdx.x;
    if (i < 512 * 128) {
        w1b[i] = f2bf(w1[i]);
        w2b[i] = f2bf(w2[i]);
    }
}

// ---------------- kernel 1: GAT + attention-softmax + conv ----------------
// one wave (64 lanes) per batch; lane = node index j (softmax) then out-channel o (conv)
__global__ __launch_bounds__(512, 4) void k1_attn_conv(
    const float* __restrict__ x,       // (B,64,2)
    const float* __restrict__ W_gat,   // (4,2)
    const float* __restrict__ a_attn,  // (8,)
    const float* __restrict__ conv_w,  // (64,64,3)
    const float* __restrict__ conv_b,  // (64,)
    float* __restrict__ enc_out,       // (B,64,2)  == flat (B,128)
    int B, int stride_waves)
{
    __shared__ float2 w01_lds[64 * 64];   // [i][o] -> (w[o][i][0], w[o][i][1])  32KB
    __shared__ float  w2c_lds[64 * 64];   // [i][o] -> w[o][i][2]                16KB
    __shared__ float  zes[8][64][8];      // per wave: z0..3, esL, esL2          16KB
    __shared__ float  h_lds[8][64][4];    //                                      8KB

    const int tid  = threadIdx.x;
    const int lane = tid & 63;
    const int wv   = tid >> 6;

    for (int idx = tid; idx < 64 * 64; idx += 512) {
        int i = idx >> 6, o = idx & 63;
        const float* wp = conv_w + o * 192 + i * 3;
        w01_lds[idx] = make_float2(wp[0], wp[1]);
        w2c_lds[idx] = wp[2];
    }
    __syncthreads();

    const float Wg00 = W_gat[0], Wg01 = W_gat[1], Wg10 = W_gat[2], Wg11 = W_gat[3];
    const float Wg20 = W_gat[4], Wg21 = W_gat[5], Wg30 = W_gat[6], Wg31 = W_gat[7];
    const float as0 = a_attn[0], as1 = a_attn[1], as2 = a_attn[2], as3 = a_attn[3];
    const float ad0 = a_attn[4], ad1 = a_attn[5], ad2 = a_attn[6], ad3 = a_attn[7];
    const float cb = conv_b[lane];
    const float L2E = 1.4426950408889634f;
    const float SL = 0.2f;

    for (int b = blockIdx.x * 8 + wv; b < B; b += stride_waves) {
        const float2 xv = ((const float2*)x)[b * 64 + lane];
        const float z0 = xv.x * Wg00 + xv.y * Wg01;
        const float z1 = xv.x * Wg10 + xv.y * Wg11;
        const float z2 = xv.x * Wg20 + xv.y * Wg21;
        const float z3 = xv.x * Wg30 + xv.y * Wg31;
        const float es = z0 * as0 + z1 * as1 + z2 * as2 + z3 * as3;
        const float ed = z0 * ad0 + z1 * ad1 + z2 * ad2 + z3 * ad3;
        const float esL  = es * L2E;
        const float esL2 = SL * esL;
        *(float4*)(&zes[wv][lane][0]) = make_float4(z0, z1, z2, z3);
        *(float2*)(&zes[wv][lane][4]) = make_float2(esL, esL2);

        // max and (exclude-one) second max of es across the wave
        float m1 = es;
        #pragma unroll
        for (int off = 32; off > 0; off >>= 1) m1 = fmaxf(m1, __shfl_xor(m1, off));
        unsigned long long msk = __ballot(es == m1);
        int first = __ffsll((unsigned long long)msk) - 1;
        float m2 = (lane == first) ? -__builtin_inff() : es;
        #pragma unroll
        for (int off = 32; off > 0; off >>= 1) m2 = fmaxf(m2, __shfl_xor(m2, off));
        const float Mj = (lane == first) ? m2 : m1;   // max_{i!=j} es_i
        const float tj = Mj + ed;
        const float mj = fmaxf(tj, SL * tj);          // lrelu is monotone => column max
        const float c1 = (ed - mj) * L2E;
        const float c2 = (SL * ed - mj) * L2E;

        float sum = 0.f, h0 = 0.f, h1 = 0.f, h2 = 0.f, h3 = 0.f;
        #pragma unroll 8
        for (int i = 0; i < 64; ++i) {
            const float4 zi = *(const float4*)(&zes[wv][i][0]);
            const float2 ei = *(const float2*)(&zes[wv][i][4]);
            const float a  = ei.x + c1;
            const float bb = ei.y + c2;
            const float p  = exp2f(fmaxf(a, bb));
            sum += p;
            h0 += p * zi.x; h1 += p * zi.y; h2 += p * zi.z; h3 += p * zi.w;
        }
        // remove the i==j (self) contribution exactly (bit-identical recompute)
        const float pS = exp2f(fmaxf(esL + c1, esL2 + c2));
        sum -= pS;
        h0 -= pS * z0; h1 -= pS * z1; h2 -= pS * z2; h3 -= pS * z3;
        const float rs = 1.0f / sum;
        *(float4*)(&h_lds[wv][lane][0]) = make_float4(h0 * rs, h1 * rs, h2 * rs, h3 * rs);

        // conv: lane = output channel o
        float a0 = 0.f, a1 = 0.f;
        #pragma unroll 8
        for (int i = 0; i < 64; ++i) {
            const float4 hv = *(const float4*)(&h_lds[wv][i][0]);
            const float2 w01 = w01_lds[i * 64 + lane];
            const float wk2 = w2c_lds[i * 64 + lane];
            a0 += hv.x * w01.x + hv.y * w01.y + hv.z * wk2;
            a1 += hv.y * w01.x + hv.z * w01.y + hv.w * wk2;
        }
        ((float2*)enc_out)[b * 64 + lane] = make_float2(a0 + cb, a1 + cb);
    }
}

// ---------------- kernel 2: decoder MLP 128 -> 512(relu) -> 128, MFMA bf16 ----------------
// block = 4 waves; wave handles 16 batch rows. Weights are the A operand (identical
// fragments across waves -> L1 reuse); batch rows are the B/N operand.
__global__ __launch_bounds__(256, 2) void k2_decoder(
    const float* __restrict__ flat,          // (B,128) f32 == encoder out
    const unsigned short* __restrict__ w1b,  // (512,128) bf16
    const unsigned short* __restrict__ w2b,  // (128,512) bf16
    const float* __restrict__ b1,            // (512,)
    const float* __restrict__ b2,            // (128,)
    float* __restrict__ dec_out)             // (B,128) f32
{
    __shared__ unsigned short H_all[4][16 * 512];   // per-wave 16x512 bf16, 64KB total
    const int tid  = threadIdx.x;
    const int lane = tid & 63;
    const int wv   = tid >> 6;
    const int r    = lane & 15;
    const int g    = lane >> 4;
    const int row_base = (blockIdx.x * 4 + wv) * 16;
    unsigned short* H = H_all[wv];
    const int swz = (r & 7) << 3;   // ushort-index XOR => byte XOR ((r&7)<<4)

    // load this wave's 16 flat rows as B-fragments (bf16)
    bf16x8 ff[4];
    {
        const float* frow = flat + (size_t)(row_base + r) * 128;
        #pragma unroll
        for (int kb = 0; kb < 4; ++kb) {
            const int k0 = kb * 32 + g * 8;
            const float4 u = *(const float4*)(frow + k0);
            const float4 v = *(const float4*)(frow + k0 + 4);
            union { bf16x8 v8; unsigned short us[8]; } cv;
            cv.us[0] = f2bf(u.x); cv.us[1] = f2bf(u.y); cv.us[2] = f2bf(u.z); cv.us[3] = f2bf(u.w);
            cv.us[4] = f2bf(v.x); cv.us[5] = f2bf(v.y); cv.us[6] = f2bf(v.z); cv.us[7] = f2bf(v.w);
            ff[kb] = cv.v8;
        }
    }

    f32x4 acc2[8];
    #pragma unroll
    for (int mb = 0; mb < 8; ++mb) acc2[mb] = (f32x4){0.f, 0.f, 0.f, 0.f};

    for (int np = 0; np < 16; ++np) {
        __syncthreads();   // keep the 4 waves together so weight loads hit L1
        #pragma unroll
        for (int t = 0; t < 2; ++t) {
            const int nb = np * 2 + t;
            f32x4 acc1 = (f32x4){0.f, 0.f, 0.f, 0.f};
            #pragma unroll
            for (int kb = 0; kb < 4; ++kb) {
                const bf16x8 wf = *(const bf16x8*)(w1b + (nb * 16 + r) * 128 + kb * 32 + g * 8);
                acc1 = __builtin_amdgcn_mfma_f32_16x16x32_bf16(wf, ff[kb], acc1, 0, 0, 0);
            }
            const int n0 = nb * 16 + g * 4;
            const float4 bias = *(const float4*)(b1 + n0);
            const float v0 = fmaxf(acc1[0] + bias.x, 0.f);
            const float v1 = fmaxf(acc1[1] + bias.y, 0.f);
            const float v2 = fmaxf(acc1[2] + bias.z, 0.f);
            const float v3 = fmaxf(acc1[3] + bias.w, 0.f);
            const unsigned int lo = (unsigned int)f2bf(v0) | ((unsigned int)f2bf(v1) << 16);
            const unsigned int hi = (unsigned int)f2bf(v2) | ((unsigned int)f2bf(v3) << 16);
            const int idx = (r * 512 + n0) ^ swz;
            *(uint2*)(&H[idx]) = make_uint2(lo, hi);
        }
        const int kidx = (r * 512 + np * 32 + g * 8) ^ swz;
        const bf16x8 hf = *(const bf16x8*)(&H[kidx]);
        #pragma unroll
        for (int mb = 0; mb < 8; ++mb) {
            const bf16x8 wf = *(const bf16x8*)(w2b + (mb * 16 + r) * 512 + np * 32 + g * 8);
            acc2[mb] = __builtin_amdgcn_mfma_f32_16x16x32_bf16(wf, hf, acc2[mb], 0, 0, 0);
        }
    }

    float* orow = dec_out + (size_t)(row_base + r) * 128;
    #pragma unroll
    for (int mb = 0; mb < 8; ++mb) {
        const int m0 = mb * 16 + g * 4;
        const float4 bias = *(const float4*)(b2 + m0);
        float4 o;
        o.x = acc2[mb][0] + bias.x;
        o.y = acc2[mb][1] + bias.y;
        o.z = acc2[mb][2] + bias.z;
        o.w = acc2[mb][3] + bias.w;
        *(float4*)(orow + m0) = o;
    }
}

extern "C" void kernel_launch(void* const* d_in, const int* in_sizes, int n_in,
                              void* d_out, int out_size, void* d_ws, size_t ws_size,
                              hipStream_t stream) {
    const float* x      = (const float*)d_in[0];
    const float* W_gat  = (const float*)d_in[1];
    const float* a_attn = (const float*)d_in[2];
    const float* conv_w = (const float*)d_in[3];
    const float* conv_b = (const float*)d_in[4];
    const float* dec_w1 = (const float*)d_in[5];
    const float* dec_b1 = (const float*)d_in[6];
    const float* dec_w2 = (const float*)d_in[7];
    const float* dec_b2 = (const float*)d_in[8];
    float* out = (float*)d_out;

    const int B = in_sizes[0] / 128;          // 16384
    unsigned short* w1b = (unsigned short*)d_ws;
    unsigned short* w2b = w1b + 512 * 128;

    k0_prep<<<256, 256, 0, stream>>>(dec_w1, dec_w2, w1b, w2b);

    const int nblocks1 = 512;                 // 8 waves each -> 4096 waves, 4 batches/wave
    k1_attn_conv<<<nblocks1, 512, 0, stream>>>(x, W_gat, a_attn, conv_w, conv_b,
                                               out, B, nblocks1 * 8);

    k2_decoder<<<B / 64, 256, 0, stream>>>(out, w1b, w2b, dec_b1, dec_b2,
                                           out + (size_t)B * 128);
}

// Round 2
// 101.821 us; speedup vs baseline: 1.0837x; 1.0837x over previous
//
#include <hip/hip_runtime.h>

// ConvAutoEncoder: B=16384, T=64, C=2, D=4
// out = [encoder_out (B*128 f32) | decoded (B*128 f32)]
// decoded region doubles as bf16 h scratch (B*256 bf16 = same 8MB) between k1 and k2.

typedef __attribute__((ext_vector_type(8))) short bf16x8;
typedef __attribute__((ext_vector_type(4))) float f32x4;

__device__ __forceinline__ unsigned short f2bf(float f) {
    unsigned int u = __builtin_bit_cast(unsigned int, f);
    return (unsigned short)((u + 0x7FFFu + ((u >> 16) & 1u)) >> 16);
}
__device__ __forceinline__ unsigned int pack2bf(float a, float b) {
    return (unsigned int)f2bf(a) | ((unsigned int)f2bf(b) << 16);
}

// ---------------- kernel 0: weight prep ----------------
// w1b (512x128 bf16), w2b (128x512 bf16), wcv (128x256 bf16 conv-as-matmul), biasf (128 f32)
__global__ void k0_prep(const float* __restrict__ w1, const float* __restrict__ w2,
                        const float* __restrict__ cw, const float* __restrict__ cb,
                        unsigned short* __restrict__ w1b, unsigned short* __restrict__ w2b,
                        unsigned short* __restrict__ wcv, float* __restrict__ biasf) {
    int i = blockIdx.x * 256 + threadIdx.x;      // 0..65535
    if (i < 512 * 128) { w1b[i] = f2bf(w1[i]); w2b[i] = f2bf(w2[i]); }
    if (i < 128 * 256) {
        int f = i >> 8, kd = i & 255;            // f = 2*o + s (flat out dim), kd = node*4 + d
        int o = f >> 1, s = f & 1, node = kd >> 2, d = kd & 3;
        int k = d - s;
        float v = (k >= 0 && k < 3) ? cw[o * 192 + node * 3 + k] : 0.f;
        wcv[i] = f2bf(v);
    }
    if (i < 128) biasf[i] = cb[i >> 1];
}

// ---------------- kernel 1: GAT + attention softmax -> h (bf16) ----------------
// one wave per batch; lane = node j. No max-subtraction: |e| small, f32 exp2 safe.
__global__ __launch_bounds__(512, 8) void k1_attn(
    const float* __restrict__ x,       // (B,64,2)
    const float* __restrict__ W_gat,   // (4,2)
    const float* __restrict__ a_attn,  // (8,)
    uint2* __restrict__ h_out,         // (B,64) -> 4 bf16 per node
    int B, int stride_waves)
{
    __shared__ float zes[8][64][8];    // z0..3, esL, esL2 ; 16KB

    const int tid  = threadIdx.x;
    const int lane = tid & 63;
    const int wv   = tid >> 6;

    const float Wg00 = W_gat[0], Wg01 = W_gat[1], Wg10 = W_gat[2], Wg11 = W_gat[3];
    const float Wg20 = W_gat[4], Wg21 = W_gat[5], Wg30 = W_gat[6], Wg31 = W_gat[7];
    const float as0 = a_attn[0], as1 = a_attn[1], as2 = a_attn[2], as3 = a_attn[3];
    const float ad0 = a_attn[4], ad1 = a_attn[5], ad2 = a_attn[6], ad3 = a_attn[7];
    const float L2E = 1.4426950408889634f;
    const float SL = 0.2f;

    for (int b = blockIdx.x * 8 + wv; b < B; b += stride_waves) {
        const float2 xv = ((const float2*)x)[b * 64 + lane];
        const float z0 = xv.x * Wg00 + xv.y * Wg01;
        const float z1 = xv.x * Wg10 + xv.y * Wg11;
        const float z2 = xv.x * Wg20 + xv.y * Wg21;
        const float z3 = xv.x * Wg30 + xv.y * Wg31;
        const float es = z0 * as0 + z1 * as1 + z2 * as2 + z3 * as3;
        const float ed = z0 * ad0 + z1 * ad1 + z2 * ad2 + z3 * ad3;
        const float esL  = es * L2E;
        const float esL2 = SL * esL;
        *(float4*)(&zes[wv][lane][0]) = make_float4(z0, z1, z2, z3);
        *(float2*)(&zes[wv][lane][4]) = make_float2(esL, esL2);

        const float c1 = ed * L2E;          // lrelu(es+ed) = max(es+ed, 0.2(es+ed))
        const float c2 = SL * ed * L2E;

        float sum = 0.f, h0 = 0.f, h1 = 0.f, h2 = 0.f, h3 = 0.f;
        #pragma unroll 8
        for (int i = 0; i < 64; ++i) {
            const float4 zi = *(const float4*)(&zes[wv][i][0]);
            const float2 ei = *(const float2*)(&zes[wv][i][4]);
            const float p = __builtin_amdgcn_exp2f(fmaxf(ei.x + c1, ei.y + c2));
            sum += p;
            h0 += p * zi.x; h1 += p * zi.y; h2 += p * zi.z; h3 += p * zi.w;
        }
        // remove i==j self term (bit-identical recompute)
        const float pS = __builtin_amdgcn_exp2f(fmaxf(esL + c1, esL2 + c2));
        sum -= pS;
        h0 -= pS * z0; h1 -= pS * z1; h2 -= pS * z2; h3 -= pS * z3;
        const float rs = 1.0f / sum;
        h_out[b * 64 + lane] = make_uint2(pack2bf(h0 * rs, h1 * rs),
                                          pack2bf(h2 * rs, h3 * rs));
    }
}

// ---------------- kernel 2: fused conv(matmul) + encoder-out + decoder MLP ----------------
// one wave per 16 batch rows; no __syncthreads. Per-wave swizzled LDS buffer for the
// two fragment transposes. All matmuls: weights = A operand, batch rows = B columns.
__global__ __launch_bounds__(256, 1) void k2_fused(
    const unsigned short* h_bf,              // (B,256) bf16  (aliases dec_out)
    const unsigned short* __restrict__ w1b,  // (512,128)
    const unsigned short* __restrict__ w2b,  // (128,512)
    const unsigned short* __restrict__ wcv,  // (128,256)
    const float* __restrict__ biasf,         // (128,)
    const float* __restrict__ b1,            // (512,)
    const float* __restrict__ b2,            // (128,)
    float* __restrict__ enc_out,             // (B,128) f32
    float* dec_out)                          // (B,128) f32 (aliases h_bf)
{
    __shared__ unsigned short buf[4][16 * 128];   // per-wave 4KB, XOR-swizzled
    const int tid = threadIdx.x, lane = tid & 63, wv = tid >> 6;
    const int r = lane & 15, g = lane >> 4;
    const int base = (blockIdx.x * 4 + wv) * 16;
    unsigned short* mybuf = buf[wv];
    const int swz = (r & 7) << 3;                 // ushort-index XOR == byte XOR ((r&7)<<4)

    // ---- conv B-fragments: lane (r,g) holds h[base+r][kc*32 + g*8 ..+8) ----
    bf16x8 hf[8];
    const unsigned short* hrow = h_bf + (size_t)(base + r) * 256 + g * 8;
    #pragma unroll
    for (int kc = 0; kc < 8; ++kc) hf[kc] = *(const bf16x8*)(hrow + kc * 32);

    // ---- conv via MFMA: (128 out) x (16 rows), K=256 ----
    f32x4 accc[8];
    #pragma unroll
    for (int fb = 0; fb < 8; ++fb) accc[fb] = (f32x4){0.f, 0.f, 0.f, 0.f};
    #pragma unroll
    for (int kc = 0; kc < 8; ++kc) {
        #pragma unroll
        for (int fb = 0; fb < 8; ++fb) {
            const bf16x8 wf = *(const bf16x8*)(wcv + (fb * 16 + r) * 256 + kc * 32 + g * 8);
            accc[fb] = __builtin_amdgcn_mfma_f32_16x16x32_bf16(wf, hf[kc], accc[fb], 0, 0, 0);
        }
    }

    // ---- conv epilogue: bias, write encoder_out, stage bf16 into swizzled LDS ----
    #pragma unroll
    for (int fb = 0; fb < 8; ++fb) {
        const int f0 = fb * 16 + g * 4;
        const float4 bs = *(const float4*)(biasf + f0);
        const float v0 = accc[fb][0] + bs.x, v1 = accc[fb][1] + bs.y;
        const float v2 = accc[fb][2] + bs.z, v3 = accc[fb][3] + bs.w;
        *(float4*)(enc_out + (size_t)(base + r) * 128 + f0) = make_float4(v0, v1, v2, v3);
        const int idx = (r * 128 + f0) ^ swz;
        *(uint2*)(&mybuf[idx]) = make_uint2(pack2bf(v0, v1), pack2bf(v2, v3));
    }
    // ---- read layer1 B-fragments (transpose via LDS) ----
    bf16x8 ff1[4];
    #pragma unroll
    for (int kb = 0; kb < 4; ++kb) {
        const int idx = (r * 128 + kb * 32 + g * 8) ^ swz;
        ff1[kb] = *(const bf16x8*)(&mybuf[idx]);
    }

    // ---- decoder: layer1 (512, relu) interleaved with layer2 (128) per K=32 chunk ----
    f32x4 acc2[8];
    #pragma unroll
    for (int mb = 0; mb < 8; ++mb) acc2[mb] = (f32x4){0.f, 0.f, 0.f, 0.f};

    for (int np = 0; np < 16; ++np) {
        #pragma unroll
        for (int t = 0; t < 2; ++t) {
            const int nb = np * 2 + t;
            f32x4 a1v = (f32x4){0.f, 0.f, 0.f, 0.f};
            #pragma unroll
            for (int kb = 0; kb < 4; ++kb) {
                const bf16x8 wf = *(const bf16x8*)(w1b + (nb * 16 + r) * 128 + kb * 32 + g * 8);
                a1v = __builtin_amdgcn_mfma_f32_16x16x32_bf16(wf, ff1[kb], a1v, 0, 0, 0);
            }
            const int n0 = nb * 16 + g * 4;
            const float4 bs = *(const float4*)(b1 + n0);
            const float v0 = fmaxf(a1v[0] + bs.x, 0.f);
            const float v1 = fmaxf(a1v[1] + bs.y, 0.f);
            const float v2 = fmaxf(a1v[2] + bs.z, 0.f);
            const float v3 = fmaxf(a1v[3] + bs.w, 0.f);
            const int idx = (r * 128 + t * 16 + g * 4) ^ swz;   // stage K-chunk local n
            *(uint2*)(&mybuf[idx]) = make_uint2(pack2bf(v0, v1), pack2bf(v2, v3));
        }
        const int kidx = (r * 128 + g * 8) ^ swz;
        const bf16x8 hf2 = *(const bf16x8*)(&mybuf[kidx]);
        #pragma unroll
        for (int mb = 0; mb < 8; ++mb) {
            const bf16x8 wf = *(const bf16x8*)(w2b + (mb * 16 + r) * 512 + np * 32 + g * 8);
            acc2[mb] = __builtin_amdgcn_mfma_f32_16x16x32_bf16(wf, hf2, acc2[mb], 0, 0, 0);
        }
    }

    // ---- decoder epilogue ----
    float* drow = dec_out + (size_t)(base + r) * 128;
    #pragma unroll
    for (int mb = 0; mb < 8; ++mb) {
        const int m0 = mb * 16 + g * 4;
        const float4 bs = *(const float4*)(b2 + m0);
        *(float4*)(drow + m0) = make_float4(acc2[mb][0] + bs.x, acc2[mb][1] + bs.y,
                                            acc2[mb][2] + bs.z, acc2[mb][3] + bs.w);
    }
}

extern "C" void kernel_launch(void* const* d_in, const int* in_sizes, int n_in,
                              void* d_out, int out_size, void* d_ws, size_t ws_size,
                              hipStream_t stream) {
    const float* x      = (const float*)d_in[0];
    const float* W_gat  = (const float*)d_in[1];
    const float* a_attn = (const float*)d_in[2];
    const float* conv_w = (const float*)d_in[3];
    const float* conv_b = (const float*)d_in[4];
    const float* dec_w1 = (const float*)d_in[5];
    const float* dec_b1 = (const float*)d_in[6];
    const float* dec_w2 = (const float*)d_in[7];
    const float* dec_b2 = (const float*)d_in[8];
    float* out = (float*)d_out;

    const int B = in_sizes[0] / 128;                 // 16384
    unsigned short* w1b = (unsigned short*)d_ws;     // 512*128
    unsigned short* w2b = w1b + 512 * 128;           // 128*512
    unsigned short* wcv = w2b + 128 * 512;           // 128*256
    float* biasf = (float*)(wcv + 128 * 256);        // 128

    // bf16 h scratch lives in the decoded-output region (same 8MB footprint)
    unsigned short* h_bf = (unsigned short*)(out + (size_t)B * 128);

    k0_prep<<<256, 256, 0, stream>>>(dec_w1, dec_w2, conv_w, conv_b, w1b, w2b, wcv, biasf);

    const int nblocks1 = 1024;                       // 8 waves each -> 8192 waves, 2 batches/wave
    k1_attn<<<nblocks1, 512, 0, stream>>>(x, W_gat, a_attn, (uint2*)h_bf, B, nblocks1 * 8);

    k2_fused<<<B / 64, 256, 0, stream>>>(h_bf, w1b, w2b, wcv, biasf, dec_b1, dec_b2,
                                         out, out + (size_t)B * 128);
}

// Round 3
// 61.483 us; speedup vs baseline: 1.7947x; 1.6561x over previous
//
#include <hip/hip_runtime.h>

// ConvAutoEncoder: B=16384, T=64, C=2, D=4
// out = [encoder_out (B*128 f32) | decoded (B*128 f32)]
// decoded region doubles as bf16 h scratch (B*256 bf16) between k1 and k2.

typedef __attribute__((ext_vector_type(8))) short bf16x8;
typedef __attribute__((ext_vector_type(4))) float f32x4;

__device__ __forceinline__ unsigned short f2bf(float f) {
    unsigned int u = __builtin_bit_cast(unsigned int, f);
    return (unsigned short)((u + 0x7FFFu + ((u >> 16) & 1u)) >> 16);
}
__device__ __forceinline__ unsigned int pack2bf(float a, float b) {
    return (unsigned int)f2bf(a) | ((unsigned int)f2bf(b) << 16);
}

// ---------------- kernel 0: weight prep ----------------
__global__ void k0_prep(const float* __restrict__ w1, const float* __restrict__ w2,
                        const float* __restrict__ cw, const float* __restrict__ cb,
                        unsigned short* __restrict__ w1b, unsigned short* __restrict__ w2b,
                        unsigned short* __restrict__ wcv, float* __restrict__ biasf) {
    int i = blockIdx.x * 256 + threadIdx.x;      // 0..65535
    if (i < 512 * 128) { w1b[i] = f2bf(w1[i]); w2b[i] = f2bf(w2[i]); }
    if (i < 128 * 256) {
        int f = i >> 8, kd = i & 255;            // f = 2*o + s, kd = node*4 + d
        int o = f >> 1, s = f & 1, node = kd >> 2, d = kd & 3;
        int k = d - s;
        float v = (k >= 0 && k < 3) ? cw[o * 192 + node * 3 + k] : 0.f;
        wcv[i] = f2bf(v);
    }
    if (i < 128) biasf[i] = cb[i >> 1];
}

// ---------------- kernel 1: GAT + attention softmax -> h (bf16) ----------------
// one wave per batch; lane = node j. exp2(max(a+c1,b+c2)) == max(u_i*U, v_i*V):
// all transcendentals hoisted out of the 64-iter loop.
__global__ __launch_bounds__(512, 8) void k1_attn(
    const float* __restrict__ x,       // (B,64,2)
    const float* __restrict__ W_gat,   // (4,2)
    const float* __restrict__ a_attn,  // (8,)
    uint2* __restrict__ h_out,         // (B,64) -> 4 bf16 per node
    int B, int stride_waves)
{
    __shared__ float zes[8][64][8];    // z0..3, u, v ; 16KB

    const int tid  = threadIdx.x;
    const int lane = tid & 63;
    const int wv   = tid >> 6;

    const float Wg00 = W_gat[0], Wg01 = W_gat[1], Wg10 = W_gat[2], Wg11 = W_gat[3];
    const float Wg20 = W_gat[4], Wg21 = W_gat[5], Wg30 = W_gat[6], Wg31 = W_gat[7];
    const float as0 = a_attn[0], as1 = a_attn[1], as2 = a_attn[2], as3 = a_attn[3];
    const float ad0 = a_attn[4], ad1 = a_attn[5], ad2 = a_attn[6], ad3 = a_attn[7];
    const float L2E = 1.4426950408889634f;
    const float SL = 0.2f;

    for (int b = blockIdx.x * 8 + wv; b < B; b += stride_waves) {
        const float2 xv = ((const float2*)x)[b * 64 + lane];
        const float z0 = xv.x * Wg00 + xv.y * Wg01;
        const float z1 = xv.x * Wg10 + xv.y * Wg11;
        const float z2 = xv.x * Wg20 + xv.y * Wg21;
        const float z3 = xv.x * Wg30 + xv.y * Wg31;
        const float es = z0 * as0 + z1 * as1 + z2 * as2 + z3 * as3;
        const float ed = z0 * ad0 + z1 * ad1 + z2 * ad2 + z3 * ad3;
        const float u = __builtin_amdgcn_exp2f(es * L2E);        // e^{es}
        const float v = __builtin_amdgcn_exp2f(es * (SL * L2E)); // e^{0.2 es}
        const float U = __builtin_amdgcn_exp2f(ed * L2E);        // e^{ed}
        const float V = __builtin_amdgcn_exp2f(ed * (SL * L2E)); // e^{0.2 ed}
        *(float4*)(&zes[wv][lane][0]) = make_float4(z0, z1, z2, z3);
        *(float2*)(&zes[wv][lane][4]) = make_float2(u, v);

        float sum = 0.f, h0 = 0.f, h1 = 0.f, h2 = 0.f, h3 = 0.f;
        #pragma unroll 8
        for (int i = 0; i < 64; ++i) {
            const float4 zi = *(const float4*)(&zes[wv][i][0]);
            const float2 uv = *(const float2*)(&zes[wv][i][4]);
            const float p = fmaxf(uv.x * U, uv.y * V);   // = exp(lrelu(es_i+ed_j))
            sum += p;
            h0 += p * zi.x; h1 += p * zi.y; h2 += p * zi.z; h3 += p * zi.w;
        }
        // remove i==j self term (bit-identical recompute)
        const float pS = fmaxf(u * U, v * V);
        sum -= pS;
        h0 -= pS * z0; h1 -= pS * z1; h2 -= pS * z2; h3 -= pS * z3;
        const float rs = 1.0f / sum;
        h_out[b * 64 + lane] = make_uint2(pack2bf(h0 * rs, h1 * rs),
                                          pack2bf(h2 * rs, h3 * rs));
    }
}

// ---------------- kernel 2: fused conv(matmul) + encoder-out + decoder MLP ----------------
// block = 8 waves, 32 rows (2 row-tiles of 16). Wave wv owns output slice:
// conv fb=wv, L1 nb=4wv..4wv+3, L2 mb=wv. Each weight fragment used for both tiles.
__global__ __launch_bounds__(512, 4) void k2_fused(
    const unsigned short* h_bf,              // (B,256) bf16 (aliases dec_out)
    const unsigned short* __restrict__ w1b,  // (512,128)
    const unsigned short* __restrict__ w2b,  // (128,512)
    const unsigned short* __restrict__ wcv,  // (128,256)
    const float* __restrict__ biasf,         // (128,)
    const float* __restrict__ b1,            // (512,)
    const float* __restrict__ b2,            // (128,)
    float* __restrict__ enc_out,             // (B,128) f32
    float* dec_out)                          // (B,128) f32 (aliases h_bf)
{
    __shared__ unsigned short flat_lds[2][16 * 128];   // 8KB, swizzled
    __shared__ unsigned short hdec_lds[2][16 * 512];   // 32KB, swizzled
    const int tid = threadIdx.x, lane = tid & 63, wv = tid >> 6;   // wv 0..7
    const int r = lane & 15, g = lane >> 4;
    const int base = blockIdx.x * 32;
    const int swz = (r & 7) << 3;            // ushort-index XOR == byte XOR ((r&7)<<4)

    // ---- conv via MFMA: wave computes fb=wv (16 of 128 flat outputs), both tiles ----
    f32x4 accc[2];
    accc[0] = (f32x4){0.f, 0.f, 0.f, 0.f};
    accc[1] = (f32x4){0.f, 0.f, 0.f, 0.f};
    const unsigned short* hrow0 = h_bf + (size_t)(base + r) * 256 + g * 8;
    const unsigned short* hrow1 = hrow0 + 16 * 256;
    #pragma unroll
    for (int kc = 0; kc < 8; ++kc) {
        const bf16x8 wf  = *(const bf16x8*)(wcv + (wv * 16 + r) * 256 + kc * 32 + g * 8);
        const bf16x8 hf0 = *(const bf16x8*)(hrow0 + kc * 32);
        const bf16x8 hf1 = *(const bf16x8*)(hrow1 + kc * 32);
        accc[0] = __builtin_amdgcn_mfma_f32_16x16x32_bf16(wf, hf0, accc[0], 0, 0, 0);
        accc[1] = __builtin_amdgcn_mfma_f32_16x16x32_bf16(wf, hf1, accc[1], 0, 0, 0);
    }
    {
        const int f0 = wv * 16 + g * 4;
        const float4 bs = *(const float4*)(biasf + f0);
        #pragma unroll
        for (int tl = 0; tl < 2; ++tl) {
            const float v0 = accc[tl][0] + bs.x, v1 = accc[tl][1] + bs.y;
            const float v2 = accc[tl][2] + bs.z, v3 = accc[tl][3] + bs.w;
            *(float4*)(enc_out + (size_t)(base + tl * 16 + r) * 128 + f0) =
                make_float4(v0, v1, v2, v3);
            const int idx = (r * 128 + f0) ^ swz;
            *(uint2*)(&flat_lds[tl][idx]) = make_uint2(pack2bf(v0, v1), pack2bf(v2, v3));
        }
    }
    __syncthreads();

    // ---- layer1: wave computes nb = 4wv..4wv+3 (64 of 512 hidden), both tiles ----
    bf16x8 ff1[2][4];
    #pragma unroll
    for (int tl = 0; tl < 2; ++tl)
        #pragma unroll
        for (int kb = 0; kb < 4; ++kb) {
            const int idx = (r * 128 + kb * 32 + g * 8) ^ swz;
            ff1[tl][kb] = *(const bf16x8*)(&flat_lds[tl][idx]);
        }
    #pragma unroll
    for (int t = 0; t < 4; ++t) {
        const int nb = wv * 4 + t;
        f32x4 a1[2];
        a1[0] = (f32x4){0.f, 0.f, 0.f, 0.f};
        a1[1] = (f32x4){0.f, 0.f, 0.f, 0.f};
        #pragma unroll
        for (int kb = 0; kb < 4; ++kb) {
            const bf16x8 wf = *(const bf16x8*)(w1b + (nb * 16 + r) * 128 + kb * 32 + g * 8);
            a1[0] = __builtin_amdgcn_mfma_f32_16x16x32_bf16(wf, ff1[0][kb], a1[0], 0, 0, 0);
            a1[1] = __builtin_amdgcn_mfma_f32_16x16x32_bf16(wf, ff1[1][kb], a1[1], 0, 0, 0);
        }
        const int n0 = nb * 16 + g * 4;
        const float4 bs = *(const float4*)(b1 + n0);
        #pragma unroll
        for (int tl = 0; tl < 2; ++tl) {
            const float v0 = fmaxf(a1[tl][0] + bs.x, 0.f);
            const float v1 = fmaxf(a1[tl][1] + bs.y, 0.f);
            const float v2 = fmaxf(a1[tl][2] + bs.z, 0.f);
            const float v3 = fmaxf(a1[tl][3] + bs.w, 0.f);
            const int idx = (r * 512 + n0) ^ swz;
            *(uint2*)(&hdec_lds[tl][idx]) = make_uint2(pack2bf(v0, v1), pack2bf(v2, v3));
        }
    }
    __syncthreads();

    // ---- layer2: wave computes mb = wv (16 of 128 outputs), both tiles ----
    f32x4 acc2[2];
    acc2[0] = (f32x4){0.f, 0.f, 0.f, 0.f};
    acc2[1] = (f32x4){0.f, 0.f, 0.f, 0.f};
    #pragma unroll
    for (int np = 0; np < 16; ++np) {
        const bf16x8 wf = *(const bf16x8*)(w2b + (wv * 16 + r) * 512 + np * 32 + g * 8);
        const int kidx = (r * 512 + np * 32 + g * 8) ^ swz;
        const bf16x8 h0 = *(const bf16x8*)(&hdec_lds[0][kidx]);
        const bf16x8 h1 = *(const bf16x8*)(&hdec_lds[1][kidx]);
        acc2[0] = __builtin_amdgcn_mfma_f32_16x16x32_bf16(wf, h0, acc2[0], 0, 0, 0);
        acc2[1] = __builtin_amdgcn_mfma_f32_16x16x32_bf16(wf, h1, acc2[1], 0, 0, 0);
    }
    {
        const int m0 = wv * 16 + g * 4;
        const float4 bs = *(const float4*)(b2 + m0);
        #pragma unroll
        for (int tl = 0; tl < 2; ++tl) {
            *(float4*)(dec_out + (size_t)(base + tl * 16 + r) * 128 + m0) =
                make_float4(acc2[tl][0] + bs.x, acc2[tl][1] + bs.y,
                            acc2[tl][2] + bs.z, acc2[tl][3] + bs.w);
        }
    }
}

extern "C" void kernel_launch(void* const* d_in, const int* in_sizes, int n_in,
                              void* d_out, int out_size, void* d_ws, size_t ws_size,
                              hipStream_t stream) {
    const float* x      = (const float*)d_in[0];
    const float* W_gat  = (const float*)d_in[1];
    const float* a_attn = (const float*)d_in[2];
    const float* conv_w = (const float*)d_in[3];
    const float* conv_b = (const float*)d_in[4];
    const float* dec_w1 = (const float*)d_in[5];
    const float* dec_b1 = (const float*)d_in[6];
    const float* dec_w2 = (const float*)d_in[7];
    const float* dec_b2 = (const float*)d_in[8];
    float* out = (float*)d_out;

    const int B = in_sizes[0] / 128;                 // 16384
    unsigned short* w1b = (unsigned short*)d_ws;     // 512*128
    unsigned short* w2b = w1b + 512 * 128;           // 128*512
    unsigned short* wcv = w2b + 128 * 512;           // 128*256
    float* biasf = (float*)(wcv + 128 * 256);        // 128

    unsigned short* h_bf = (unsigned short*)(out + (size_t)B * 128);

    k0_prep<<<256, 256, 0, stream>>>(dec_w1, dec_w2, conv_w, conv_b, w1b, w2b, wcv, biasf);

    const int nblocks1 = 1024;                       // 8 waves each: 2 batches/wave
    k1_attn<<<nblocks1, 512, 0, stream>>>(x, W_gat, a_attn, (uint2*)h_bf, B, nblocks1 * 8);

    k2_fused<<<B / 32, 512, 0, stream>>>(h_bf, w1b, w2b, wcv, biasf, dec_b1, dec_b2,
                                         out, out + (size_t)B * 128);
}

// Round 4
// 58.345 us; speedup vs baseline: 1.8912x; 1.0538x over previous
//
#include <hip/hip_runtime.h>

// ConvAutoEncoder: B=16384, T=64, C=2, D=4
// out = [encoder_out (B*128 f32) | decoded (B*128 f32)]
// Single fused kernel: attention (VALU, packed-f32) -> conv/decoder (MFMA) per 16-batch tile.

typedef __attribute__((ext_vector_type(8))) short bf16x8;
typedef __attribute__((ext_vector_type(4))) float f32x4;

__device__ __forceinline__ unsigned short f2bf(float f) {
    unsigned int u = __builtin_bit_cast(unsigned int, f);
    return (unsigned short)((u + 0x7FFFu + ((u >> 16) & 1u)) >> 16);
}
__device__ __forceinline__ unsigned int pack2bf(float a, float b) {
    return (unsigned int)f2bf(a) | ((unsigned int)f2bf(b) << 16);
}

#define SWZ(row) (((row) & 7) << 3)   // ushort-index XOR == byte XOR ((row&7)<<4)

// ---------------- kernel 0: weight prep ----------------
__global__ void k0_prep(const float* __restrict__ w1, const float* __restrict__ w2,
                        const float* __restrict__ cw, const float* __restrict__ cb,
                        unsigned short* __restrict__ w1b, unsigned short* __restrict__ w2b,
                        unsigned short* __restrict__ wcv, float* __restrict__ biasf) {
    int i = blockIdx.x * 256 + threadIdx.x;      // 0..65535
    if (i < 512 * 128) { w1b[i] = f2bf(w1[i]); w2b[i] = f2bf(w2[i]); }
    if (i < 128 * 256) {
        int f = i >> 8, kd = i & 255;            // f = 2*o + s, kd = node*4 + d
        int o = f >> 1, s = f & 1, node = kd >> 2, d = kd & 3;
        int k = d - s;
        float v = (k >= 0 && k < 3) ? cw[o * 192 + node * 3 + k] : 0.f;
        wcv[i] = f2bf(v);
    }
    if (i < 128) biasf[i] = cb[i >> 1];
}

// ---------------- fused kernel ----------------
// block = 4 waves, 16 batches. Attention: wave wv handles local rows 4wv..4wv+3,
// SoA scratch + f32x4 packed math, h -> swizzled LDS bf16.
// Then conv (fb = wv, wv+4), L1 (nb = 8wv..8wv+7), L2 (mb = wv, wv+4) via MFMA.
__global__ __launch_bounds__(256, 5) void k_fused(
    const float* __restrict__ x,             // (B,64,2)
    const float* __restrict__ W_gat,         // (4,2)
    const float* __restrict__ a_attn,        // (8,)
    const unsigned short* __restrict__ w1b,  // (512,128)
    const unsigned short* __restrict__ w2b,  // (128,512)
    const unsigned short* __restrict__ wcv,  // (128,256)
    const float* __restrict__ biasf,         // (128,)
    const float* __restrict__ b1,            // (512,)
    const float* __restrict__ b2,            // (128,)
    float* __restrict__ enc_out,             // (B,128) f32
    float* __restrict__ dec_out)             // (B,128) f32
{
    __shared__ __align__(16) unsigned char smem[28672];
    unsigned short* h_lds    = (unsigned short*)smem;            // [16][256] bf16 swz, 8KB
    unsigned short* flat_lds = (unsigned short*)(smem + 8192);   // [16][128] bf16 swz, 4KB
    float*          zes      = (float*)(smem + 12288);           // [4][6][64] f32, 6KB   } aliased
    unsigned short* hdec_lds = (unsigned short*)(smem + 12288);  // [16][512] bf16 swz, 16KB }

    const int tid = threadIdx.x, lane = tid & 63, wv = tid >> 6;  // wv 0..3
    const int r = lane & 15, g = lane >> 4;
    const int base = blockIdx.x * 16;

    // ================= attention =================
    {
        const float Wg00 = W_gat[0], Wg01 = W_gat[1], Wg10 = W_gat[2], Wg11 = W_gat[3];
        const float Wg20 = W_gat[4], Wg21 = W_gat[5], Wg30 = W_gat[6], Wg31 = W_gat[7];
        const float as0 = a_attn[0], as1 = a_attn[1], as2 = a_attn[2], as3 = a_attn[3];
        const float ad0 = a_attn[4], ad1 = a_attn[5], ad2 = a_attn[6], ad3 = a_attn[7];
        const float L2E = 1.4426950408889634f;
        const float SL = 0.2f;

        float* Z0 = zes + wv * 384;
        float* Z1 = Z0 + 64; float* Z2 = Z0 + 128; float* Z3 = Z0 + 192;
        float* Uu = Z0 + 256; float* Vv = Z0 + 320;

        float2 xv = ((const float2*)x)[(size_t)(base + wv * 4) * 64 + lane];
        #pragma unroll
        for (int t = 0; t < 4; ++t) {
            const int lr = wv * 4 + t;
            float2 xv_n;
            if (t < 3) xv_n = ((const float2*)x)[(size_t)(base + lr + 1) * 64 + lane];

            const float z0 = xv.x * Wg00 + xv.y * Wg01;
            const float z1 = xv.x * Wg10 + xv.y * Wg11;
            const float z2 = xv.x * Wg20 + xv.y * Wg21;
            const float z3 = xv.x * Wg30 + xv.y * Wg31;
            const float es = z0 * as0 + z1 * as1 + z2 * as2 + z3 * as3;
            const float ed = z0 * ad0 + z1 * ad1 + z2 * ad2 + z3 * ad3;
            const float u = __builtin_amdgcn_exp2f(es * L2E);         // e^{es}
            const float v = __builtin_amdgcn_exp2f(es * (SL * L2E));  // e^{0.2 es}
            const float U = __builtin_amdgcn_exp2f(ed * L2E);
            const float V = __builtin_amdgcn_exp2f(ed * (SL * L2E));
            Z0[lane] = z0; Z1[lane] = z1; Z2[lane] = z2; Z3[lane] = z3;
            Uu[lane] = u;  Vv[lane] = v;

            const f32x4 U4 = {U, U, U, U}, V4 = {V, V, V, V};
            f32x4 S  = {0.f, 0.f, 0.f, 0.f};
            f32x4 H0 = S, H1 = S, H2 = S, H3 = S;
            #pragma unroll 2
            for (int i4 = 0; i4 < 16; ++i4) {
                const f32x4 vz0 = *(const f32x4*)(Z0 + i4 * 4);
                const f32x4 vz1 = *(const f32x4*)(Z1 + i4 * 4);
                const f32x4 vz2 = *(const f32x4*)(Z2 + i4 * 4);
                const f32x4 vz3 = *(const f32x4*)(Z3 + i4 * 4);
                const f32x4 vu  = *(const f32x4*)(Uu + i4 * 4);
                const f32x4 vv  = *(const f32x4*)(Vv + i4 * 4);
                const f32x4 P = __builtin_elementwise_max(vu * U4, vv * V4);
                S += P;
                H0 += P * vz0; H1 += P * vz1; H2 += P * vz2; H3 += P * vz3;
            }
            // remove i==j self term (same f32 ops -> bit-identical value)
            const float pS = fmaxf(u * U, v * V);
            const float sum = (S[0] + S[1]) + (S[2] + S[3]) - pS;
            const float h0 = (H0[0] + H0[1]) + (H0[2] + H0[3]) - pS * z0;
            const float h1 = (H1[0] + H1[1]) + (H1[2] + H1[3]) - pS * z1;
            const float h2 = (H2[0] + H2[1]) + (H2[2] + H2[3]) - pS * z2;
            const float h3 = (H3[0] + H3[1]) + (H3[2] + H3[3]) - pS * z3;
            const float rs = 1.0f / sum;
            const int hidx = (lr * 256 + lane * 4) ^ SWZ(lr);
            *(uint2*)(&h_lds[hidx]) = make_uint2(pack2bf(h0 * rs, h1 * rs),
                                                 pack2bf(h2 * rs, h3 * rs));
            xv = xv_n;
        }
    }
    __syncthreads();

    // ================= conv (as matmul, K=256) =================
    f32x4 accc[2];
    accc[0] = (f32x4){0.f, 0.f, 0.f, 0.f};
    accc[1] = (f32x4){0.f, 0.f, 0.f, 0.f};
    #pragma unroll
    for (int kc = 0; kc < 8; ++kc) {
        const bf16x8 hf  = *(const bf16x8*)(&h_lds[(r * 256 + kc * 32 + g * 8) ^ SWZ(r)]);
        const bf16x8 wfa = *(const bf16x8*)(wcv + (wv * 16 + r) * 256 + kc * 32 + g * 8);
        const bf16x8 wfb = *(const bf16x8*)(wcv + ((wv + 4) * 16 + r) * 256 + kc * 32 + g * 8);
        accc[0] = __builtin_amdgcn_mfma_f32_16x16x32_bf16(wfa, hf, accc[0], 0, 0, 0);
        accc[1] = __builtin_amdgcn_mfma_f32_16x16x32_bf16(wfb, hf, accc[1], 0, 0, 0);
    }
    #pragma unroll
    for (int q = 0; q < 2; ++q) {
        const int f0 = (wv + q * 4) * 16 + g * 4;
        const float4 bs = *(const float4*)(biasf + f0);
        const float v0 = accc[q][0] + bs.x, v1 = accc[q][1] + bs.y;
        const float v2 = accc[q][2] + bs.z, v3 = accc[q][3] + bs.w;
        *(float4*)(enc_out + (size_t)(base + r) * 128 + f0) = make_float4(v0, v1, v2, v3);
        const int fidx = (r * 128 + f0) ^ SWZ(r);
        *(uint2*)(&flat_lds[fidx]) = make_uint2(pack2bf(v0, v1), pack2bf(v2, v3));
    }
    __syncthreads();

    // ================= decoder layer1: 128 -> 512, relu =================
    bf16x8 ff1[4];
    #pragma unroll
    for (int kb = 0; kb < 4; ++kb)
        ff1[kb] = *(const bf16x8*)(&flat_lds[(r * 128 + kb * 32 + g * 8) ^ SWZ(r)]);
    #pragma unroll
    for (int t = 0; t < 8; ++t) {
        const int nb = wv * 8 + t;
        f32x4 a1 = (f32x4){0.f, 0.f, 0.f, 0.f};
        #pragma unroll
        for (int kb = 0; kb < 4; ++kb) {
            const bf16x8 wf = *(const bf16x8*)(w1b + (nb * 16 + r) * 128 + kb * 32 + g * 8);
            a1 = __builtin_amdgcn_mfma_f32_16x16x32_bf16(wf, ff1[kb], a1, 0, 0, 0);
        }
        const int n0 = nb * 16 + g * 4;
        const float4 bs = *(const float4*)(b1 + n0);
        const float v0 = fmaxf(a1[0] + bs.x, 0.f);
        const float v1 = fmaxf(a1[1] + bs.y, 0.f);
        const float v2 = fmaxf(a1[2] + bs.z, 0.f);
        const float v3 = fmaxf(a1[3] + bs.w, 0.f);
        const int hdidx = (r * 512 + n0) ^ SWZ(r);
        *(uint2*)(&hdec_lds[hdidx]) = make_uint2(pack2bf(v0, v1), pack2bf(v2, v3));
    }
    __syncthreads();

    // ================= decoder layer2: 512 -> 128 =================
    f32x4 acc2[2];
    acc2[0] = (f32x4){0.f, 0.f, 0.f, 0.f};
    acc2[1] = (f32x4){0.f, 0.f, 0.f, 0.f};
    #pragma unroll
    for (int np = 0; np < 16; ++np) {
        const bf16x8 hfd = *(const bf16x8*)(&hdec_lds[(r * 512 + np * 32 + g * 8) ^ SWZ(r)]);
        const bf16x8 wfa = *(const bf16x8*)(w2b + (wv * 16 + r) * 512 + np * 32 + g * 8);
        const bf16x8 wfb = *(const bf16x8*)(w2b + ((wv + 4) * 16 + r) * 512 + np * 32 + g * 8);
        acc2[0] = __builtin_amdgcn_mfma_f32_16x16x32_bf16(wfa, hfd, acc2[0], 0, 0, 0);
        acc2[1] = __builtin_amdgcn_mfma_f32_16x16x32_bf16(wfb, hfd, acc2[1], 0, 0, 0);
    }
    #pragma unroll
    for (int q = 0; q < 2; ++q) {
        const int m0 = (wv + q * 4) * 16 + g * 4;
        const float4 bs = *(const float4*)(b2 + m0);
        *(float4*)(dec_out + (size_t)(base + r) * 128 + m0) =
            make_float4(acc2[q][0] + bs.x, acc2[q][1] + bs.y,
                        acc2[q][2] + bs.z, acc2[q][3] + bs.w);
    }
}

extern "C" void kernel_launch(void* const* d_in, const int* in_sizes, int n_in,
                              void* d_out, int out_size, void* d_ws, size_t ws_size,
                              hipStream_t stream) {
    const float* x      = (const float*)d_in[0];
    const float* W_gat  = (const float*)d_in[1];
    const float* a_attn = (const float*)d_in[2];
    const float* conv_w = (const float*)d_in[3];
    const float* conv_b = (const float*)d_in[4];
    const float* dec_w1 = (const float*)d_in[5];
    const float* dec_b1 = (const float*)d_in[6];
    const float* dec_w2 = (const float*)d_in[7];
    const float* dec_b2 = (const float*)d_in[8];
    float* out = (float*)d_out;

    const int B = in_sizes[0] / 128;                 // 16384
    unsigned short* w1b = (unsigned short*)d_ws;     // 512*128
    unsigned short* w2b = w1b + 512 * 128;           // 128*512
    unsigned short* wcv = w2b + 128 * 512;           // 128*256
    float* biasf = (float*)(wcv + 128 * 256);        // 128

    k0_prep<<<256, 256, 0, stream>>>(dec_w1, dec_w2, conv_w, conv_b, w1b, w2b, wcv, biasf);

    k_fused<<<B / 16, 256, 0, stream>>>(x, W_gat, a_attn, w1b, w2b, wcv, biasf,
                                        dec_b1, dec_b2, out, out + (size_t)B * 128);
}